// Round 2
// baseline (571.619 us; speedup 1.0000x reference)
//
#include <hip/hip_runtime.h>
#include <hip/hip_bf16.h>
#include <math.h>

// Problem: B=16384, D_IN=512, H=512
//   z = GroupNorm4(cat(x,h) @ W + b) ; FiLM(u) ; LSTM gates ; c_new ;
//   cn = GroupNorm1(c_new)*gamma+beta ; h_new = sig(o)*tanh(cn)
// Outputs: [h_new (16384x512) ; c_new (16384x512)] fp32 flat.

typedef __attribute__((ext_vector_type(8))) short bf16x8;   // 8 bf16 = 4 VGPRs
typedef __attribute__((ext_vector_type(4))) float f32x4;

static constexpr int Bn = 16384;
static constexpr int K  = 1024;   // D_IN + H
static constexpr int N  = 2048;   // 4*H
static constexpr int H  = 512;

// round-to-nearest-even f32 -> bf16 (inputs are finite; no NaN path needed)
__device__ __forceinline__ unsigned short f2bf(float f) {
  unsigned int u = __builtin_bit_cast(unsigned int, f);
  u += 0x7FFFu + ((u >> 16) & 1u);
  return (unsigned short)(u >> 16);
}
__device__ __forceinline__ float bf2f(unsigned short s) {
  unsigned int u = ((unsigned int)s) << 16;
  return __builtin_bit_cast(float, u);
}

// ---------------- prep: A = bf16(cat(x,h))  [16384][1024] ----------------
__global__ void prep_a(const float* __restrict__ x, const float* __restrict__ h,
                       unsigned short* __restrict__ A) {
  const int total = Bn * (K / 4);  // items of 4 elems
  for (int idx = blockIdx.x * blockDim.x + threadIdx.x; idx < total;
       idx += gridDim.x * blockDim.x) {
    int row = idx >> 8;          // K/4 = 256 items per row
    int k = (idx & 255) * 4;
    const float* src = (k < 512) ? (x + (size_t)row * 512 + k)
                                 : (h + (size_t)row * 512 + (k - 512));
    float4 v = *reinterpret_cast<const float4*>(src);
    ushort4 o;
    o.x = f2bf(v.x); o.y = f2bf(v.y); o.z = f2bf(v.z); o.w = f2bf(v.w);
    *reinterpret_cast<ushort4*>(A + (size_t)row * K + k) = o;
  }
}

// ---------------- prep: Bt[n][k] = bf16(W[k][n])  [2048][1024] ----------------
__global__ void prep_bt(const float* __restrict__ W, unsigned short* __restrict__ Bt) {
  __shared__ unsigned short tile[32][33];  // +1 pad
  const int n0 = blockIdx.x * 32;
  const int k0 = blockIdx.y * 32;
  const int tx = threadIdx.x;  // 0..31
  const int ty = threadIdx.y;  // 0..7
#pragma unroll
  for (int i = 0; i < 4; i++) {
    int k = k0 + ty + i * 8;
    tile[ty + i * 8][tx] = f2bf(W[(size_t)k * N + n0 + tx]);  // coalesced over n
  }
  __syncthreads();
#pragma unroll
  for (int i = 0; i < 4; i++) {
    int n = n0 + ty + i * 8;
    Bt[(size_t)n * K + k0 + tx] = tile[tx][ty + i * 8];       // coalesced over k
  }
}

// ---------------- GEMM: Z(bf16) = A @ Bt^T + b_lin ----------------
// 128x128 tile, BK=32, 4 waves (2x2), each wave 64x64 = 4x4 frags of 16x16x32.
__global__ __launch_bounds__(256, 2) void gemm_bt(
    const unsigned short* __restrict__ A,   // [16384][1024]
    const unsigned short* __restrict__ Bt,  // [2048][1024]
    const float* __restrict__ blin,         // [2048]
    unsigned short* __restrict__ Z) {       // [16384][2048] bf16
  __shared__ unsigned short As[128 * 32];
  __shared__ unsigned short Bs[128 * 32];
  const int tid = threadIdx.x;
  const int lane = tid & 63;
  const int wid = tid >> 6;
  const int wr = wid >> 1, wc = wid & 1;
  const int m0 = blockIdx.y * 128;
  const int n0 = blockIdx.x * 128;
  const int l15 = lane & 15;
  const int lk = (lane >> 4) * 8;   // K-offset of this lane's 8-elem fragment

  f32x4 acc[4][4] = {};

  for (int k0 = 0; k0 < K; k0 += 32) {
    __syncthreads();  // previous iter's LDS reads done
#pragma unroll
    for (int j = 0; j < 2; j++) {
      int t = j * 256 + tid;       // 512 items of 16B per tile
      int row = t >> 2;            // 4 items per 32-elem row
      int col = (t & 3) * 8;
      *reinterpret_cast<int4*>(&As[row * 32 + col]) =
          *reinterpret_cast<const int4*>(&A[(size_t)(m0 + row) * K + k0 + col]);
      *reinterpret_cast<int4*>(&Bs[row * 32 + col]) =
          *reinterpret_cast<const int4*>(&Bt[(size_t)(n0 + row) * K + k0 + col]);
    }
    __syncthreads();
    bf16x8 a[4], b[4];
#pragma unroll
    for (int fm = 0; fm < 4; fm++)
      a[fm] = *reinterpret_cast<const bf16x8*>(&As[(wr * 64 + fm * 16 + l15) * 32 + lk]);
#pragma unroll
    for (int fn = 0; fn < 4; fn++)
      b[fn] = *reinterpret_cast<const bf16x8*>(&Bs[(wc * 64 + fn * 16 + l15) * 32 + lk]);
#pragma unroll
    for (int fm = 0; fm < 4; fm++)
#pragma unroll
      for (int fn = 0; fn < 4; fn++)
        acc[fm][fn] = __builtin_amdgcn_mfma_f32_16x16x32_bf16(a[fm], b[fn], acc[fm][fn], 0, 0, 0);
  }

  // epilogue: D row=(lane>>4)*4+j, col=lane&15 (m89-verified)
  const int orow = (lane >> 4) * 4;
#pragma unroll
  for (int fm = 0; fm < 4; fm++) {
#pragma unroll
    for (int fn = 0; fn < 4; fn++) {
      int col = n0 + wc * 64 + fn * 16 + l15;
      float bl = blin[col];
#pragma unroll
      for (int j = 0; j < 4; j++) {
        int row = m0 + wr * 64 + fm * 16 + orow + j;
        Z[(size_t)row * N + col] = f2bf(acc[fm][fn][j] + bl);
      }
    }
  }
}

// ---------------- fused tail: GN4 + FiLM + gates + GN1 + outputs ----------------
// one row per block, 512 threads (channel j). Gate split == group split, so
// thread j holds i,f,o,g locally after the per-group normalization.
__global__ __launch_bounds__(512) void fused_tail(
    const unsigned short* __restrict__ Z,  // [16384][2048] bf16
    const float* __restrict__ u,           // [16384][4096]
    const float* __restrict__ c,           // [16384][512]
    const float* __restrict__ gamma, const float* __restrict__ beta,
    float* __restrict__ out) {             // [h_new ; c_new]
  const int m = blockIdx.x;
  const int j = threadIdx.x;   // 0..511
  const int lane = j & 63;
  const int wid = j >> 6;      // 0..7
  __shared__ float s_sum[4][8], s_sq[4][8];
  __shared__ float s2_sum[8], s2_sq[8];

  float zf[4];
#pragma unroll
  for (int g = 0; g < 4; g++)
    zf[g] = bf2f(Z[(size_t)m * N + g * H + j]);

  // 4 group reductions (sum, sumsq)
#pragma unroll
  for (int g = 0; g < 4; g++) {
    float s = zf[g], q = zf[g] * zf[g];
#pragma unroll
    for (int off = 32; off >= 1; off >>= 1) {
      s += __shfl_xor(s, off, 64);
      q += __shfl_xor(q, off, 64);
    }
    if (lane == 0) { s_sum[g][wid] = s; s_sq[g][wid] = q; }
  }
  __syncthreads();
  float zfilm[4];
#pragma unroll
  for (int g = 0; g < 4; g++) {
    float s = 0.f, q = 0.f;
#pragma unroll
    for (int w = 0; w < 8; w++) { s += s_sum[g][w]; q += s_sq[g][w]; }
    float mu = s * (1.0f / 512.0f);
    float var = q * (1.0f / 512.0f) - mu * mu;   // biased
    float rs = rsqrtf(var + 1e-5f);
    float a = u[(size_t)m * 4096 + g * H + j];
    float b = u[(size_t)m * 4096 + 2048 + g * H + j];
    zfilm[g] = (zf[g] - mu) * rs * (1.0f + a) + b;
  }
  const float ig = 1.f / (1.f + expf(-zfilm[0]));
  const float fg = 1.f / (1.f + expf(-zfilm[1]));
  const float og = 1.f / (1.f + expf(-zfilm[2]));
  const float gg = tanhf(zfilm[3]);
  const float cnew = fg * c[(size_t)m * H + j] + ig * gg;

  // second norm over the row's 512 c_new values
  {
    float s = cnew, q = cnew * cnew;
#pragma unroll
    for (int off = 32; off >= 1; off >>= 1) {
      s += __shfl_xor(s, off, 64);
      q += __shfl_xor(q, off, 64);
    }
    if (lane == 0) { s2_sum[wid] = s; s2_sq[wid] = q; }
  }
  __syncthreads();
  float s = 0.f, q = 0.f;
#pragma unroll
  for (int w = 0; w < 8; w++) { s += s2_sum[w]; q += s2_sq[w]; }
  float mu = s * (1.0f / 512.0f);
  float var = q * (1.0f / 512.0f) - mu * mu;
  float cnorm = (cnew - mu) * rsqrtf(var + 1e-5f) * gamma[j] + beta[j];
  float hn = og * tanhf(cnorm);

  out[(size_t)m * H + j] = hn;
  out[(size_t)Bn * H + (size_t)m * H + j] = cnew;
}

extern "C" void kernel_launch(void* const* d_in, const int* in_sizes, int n_in,
                              void* d_out, int out_size, void* d_ws, size_t ws_size,
                              hipStream_t stream) {
  const float* x     = (const float*)d_in[0];
  const float* h     = (const float*)d_in[1];
  const float* c     = (const float*)d_in[2];
  const float* u     = (const float*)d_in[3];
  const float* W     = (const float*)d_in[4];
  const float* blin  = (const float*)d_in[5];
  const float* gamma = (const float*)d_in[6];
  const float* beta  = (const float*)d_in[7];
  float* out = (float*)d_out;

  // workspace layout (bytes): A_bf16 32MB | Bt_bf16 4MB | Z_bf16 64MB  (~100MB)
  unsigned short* A  = (unsigned short*)d_ws;
  unsigned short* Bt = A + (size_t)Bn * K;
  unsigned short* Z  = Bt + (size_t)N * K;

  prep_a<<<2048, 256, 0, stream>>>(x, h, A);
  prep_bt<<<dim3(N / 32, K / 32), dim3(32, 8), 0, stream>>>(W, Bt);
  gemm_bt<<<dim3(N / 128, Bn / 128), 256, 0, stream>>>(A, Bt, blin, Z);
  fused_tail<<<Bn, 512, 0, stream>>>(Z, u, c, gamma, beta, out);
}

// Round 6
// 533.896 us; speedup vs baseline: 1.0707x; 1.0707x over previous
//
#include <hip/hip_runtime.h>
#include <hip/hip_bf16.h>
#include <math.h>

// Problem: B=16384, C fused cell. Outputs [h_new; c_new] fp32 flat.
// R2 changes: (1) gemm staging via global_load_lds width=16 (m97 structure),
// (2) gemm epilogue LDS-bounce -> coalesced 16B stores,
// (3) fused tail: 1 wave/row, 8 ch/lane, all loads vectorized, shuffle-only reductions.

typedef __attribute__((ext_vector_type(8))) short bf16x8;   // 8 bf16 = 4 VGPRs
typedef __attribute__((ext_vector_type(4))) float f32x4;

static constexpr int Bn = 16384;
static constexpr int K  = 1024;   // D_IN + H
static constexpr int N  = 2048;   // 4*H
static constexpr int H  = 512;

__device__ __forceinline__ unsigned short f2bf(float f) {
  unsigned int u = __builtin_bit_cast(unsigned int, f);
  u += 0x7FFFu + ((u >> 16) & 1u);
  return (unsigned short)(u >> 16);
}
__device__ __forceinline__ float bf2f(unsigned short s) {
  unsigned int u = ((unsigned int)s) << 16;
  return __builtin_bit_cast(float, u);
}
__device__ __forceinline__ float fsig(float x) {
  return 1.0f / (1.0f + __expf(-x));
}
__device__ __forceinline__ float ftanh(float x) {
  // 1 - 2/(1+e^{2x}); correct limits at +/-inf via fp32 overflow to inf
  return 1.0f - 2.0f / (1.0f + __expf(2.0f * x));
}

// ---------------- prep: A = bf16(cat(x,h))  [16384][1024] ----------------
__global__ void prep_a(const float* __restrict__ x, const float* __restrict__ h,
                       unsigned short* __restrict__ A) {
  const int total = Bn * (K / 4);
  for (int idx = blockIdx.x * blockDim.x + threadIdx.x; idx < total;
       idx += gridDim.x * blockDim.x) {
    int row = idx >> 8;
    int k = (idx & 255) * 4;
    const float* src = (k < 512) ? (x + (size_t)row * 512 + k)
                                 : (h + (size_t)row * 512 + (k - 512));
    float4 v = *reinterpret_cast<const float4*>(src);
    ushort4 o;
    o.x = f2bf(v.x); o.y = f2bf(v.y); o.z = f2bf(v.z); o.w = f2bf(v.w);
    *reinterpret_cast<ushort4*>(A + (size_t)row * K + k) = o;
  }
}

// ---------------- prep: Bt[n][k] = bf16(W[k][n])  [2048][1024] ----------------
__global__ void prep_bt(const float* __restrict__ W, unsigned short* __restrict__ Bt) {
  __shared__ unsigned short tile[32][33];
  const int n0 = blockIdx.x * 32;
  const int k0 = blockIdx.y * 32;
  const int tx = threadIdx.x;
  const int ty = threadIdx.y;
#pragma unroll
  for (int i = 0; i < 4; i++) {
    int k = k0 + ty + i * 8;
    tile[ty + i * 8][tx] = f2bf(W[(size_t)k * N + n0 + tx]);
  }
  __syncthreads();
#pragma unroll
  for (int i = 0; i < 4; i++) {
    int n = n0 + ty + i * 8;
    Bt[(size_t)n * K + k0 + tx] = tile[tx][ty + i * 8];
  }
}

// ---------------- GEMM: Z(bf16) = A @ Bt^T + b_lin ----------------
// m97 structure: 128x128 tile, BK=32, 4 waves (2x2), global_load_lds width=16,
// 2-barrier K-loop, LDS-bounce epilogue for coalesced stores.
__global__ __launch_bounds__(256, 2) void gemm_bt(
    const unsigned short* __restrict__ A,   // [16384][1024]
    const unsigned short* __restrict__ Bt,  // [2048][1024]
    const float* __restrict__ blin,         // [2048]
    unsigned short* __restrict__ Z) {       // [16384][2048] bf16
  // smem: K-loop view As[128*32] | Bs[128*32]; epilogue view Cs[128][136]
  __shared__ unsigned short smem[128 * 136];
  unsigned short* As = smem;
  unsigned short* Bs = smem + 128 * 32;
  const int tid = threadIdx.x;
  const int lane = tid & 63;
  const int wid = tid >> 6;
  const int wr = wid >> 1, wc = wid & 1;
  const int m0 = blockIdx.y * 128;
  const int n0 = blockIdx.x * 128;
  const int l15 = lane & 15;
  const int lk = (lane >> 4) * 8;

  f32x4 acc[4][4] = {};

  for (int k0 = 0; k0 < K; k0 += 32) {
    __syncthreads();  // prior iter's ds_reads done before overwrite
#pragma unroll
    for (int j = 0; j < 2; j++) {
      int item = j * 256 + tid;     // within wave: base + lane -> dest = base16 + lane*16
      int row = item >> 2;
      int kb = (item & 3) * 8;
      __builtin_amdgcn_global_load_lds(
          (const __attribute__((address_space(1))) void*)&A[(size_t)(m0 + row) * K + k0 + kb],
          (__attribute__((address_space(3))) void*)&As[item * 8], 16, 0, 0);
      __builtin_amdgcn_global_load_lds(
          (const __attribute__((address_space(1))) void*)&Bt[(size_t)(n0 + row) * K + k0 + kb],
          (__attribute__((address_space(3))) void*)&Bs[item * 8], 16, 0, 0);
    }
    __syncthreads();  // compiler drains vmcnt(0) here -> tiles ready
    bf16x8 a[4], b[4];
#pragma unroll
    for (int fm = 0; fm < 4; fm++)
      a[fm] = *reinterpret_cast<const bf16x8*>(&As[(wr * 64 + fm * 16 + l15) * 32 + lk]);
#pragma unroll
    for (int fn = 0; fn < 4; fn++)
      b[fn] = *reinterpret_cast<const bf16x8*>(&Bs[(wc * 64 + fn * 16 + l15) * 32 + lk]);
#pragma unroll
    for (int fm = 0; fm < 4; fm++)
#pragma unroll
      for (int fn = 0; fn < 4; fn++)
        acc[fm][fn] = __builtin_amdgcn_mfma_f32_16x16x32_bf16(a[fm], b[fn], acc[fm][fn], 0, 0, 0);
  }

  // epilogue: acc -> LDS (row-major, stride 136 to spread banks) -> coalesced 16B stores
  __syncthreads();
  const int orow = (lane >> 4) * 4;
#pragma unroll
  for (int fn = 0; fn < 4; fn++) {
    float bl = blin[n0 + wc * 64 + fn * 16 + l15];
#pragma unroll
    for (int fm = 0; fm < 4; fm++) {
#pragma unroll
      for (int j = 0; j < 4; j++) {
        smem[(wr * 64 + fm * 16 + orow + j) * 136 + wc * 64 + fn * 16 + l15] =
            f2bf(acc[fm][fn][j] + bl);
      }
    }
  }
  __syncthreads();
#pragma unroll
  for (int it = 0; it < 8; it++) {
    int item = it * 256 + tid;      // 2048 items of 16B (128 rows x 16 items)
    int row = item >> 4;
    int cb = (item & 15) * 8;
    int4 v = *reinterpret_cast<const int4*>(&smem[row * 136 + cb]);
    *reinterpret_cast<int4*>(&Z[(size_t)(m0 + row) * N + n0 + cb]) = v;
  }
}

// ---------------- fused tail: GN4 + FiLM + gates + GN1 + outputs ----------------
// 1 wave per row, 8 channels per lane; all loads 16-32B/lane; shuffle-only reductions.
__global__ __launch_bounds__(256) void fused_tail(
    const unsigned short* __restrict__ Z,  // [16384][2048] bf16
    const float* __restrict__ u,           // [16384][4096]
    const float* __restrict__ c,           // [16384][512]
    const float* __restrict__ gamma, const float* __restrict__ beta,
    float* __restrict__ out) {             // [h_new ; c_new]
  const int lane = threadIdx.x & 63;
  const int m = blockIdx.x * 4 + (threadIdx.x >> 6);
  const int j0 = lane * 8;

  float zfilm[4][8];
#pragma unroll
  for (int g = 0; g < 4; g++) {
    bf16x8 v = *reinterpret_cast<const bf16x8*>(&Z[(size_t)m * N + g * H + j0]);
    float zf[8];
    float s = 0.f, q = 0.f;
#pragma unroll
    for (int r = 0; r < 8; r++) {
      zf[r] = bf2f((unsigned short)v[r]);
      s += zf[r]; q += zf[r] * zf[r];
    }
#pragma unroll
    for (int off = 32; off >= 1; off >>= 1) {
      s += __shfl_xor(s, off, 64);
      q += __shfl_xor(q, off, 64);
    }
    float mu = s * (1.0f / 512.0f);
    float rs = rsqrtf(q * (1.0f / 512.0f) - mu * mu + 1e-5f);
    float4 a0 = *reinterpret_cast<const float4*>(&u[(size_t)m * 4096 + g * H + j0]);
    float4 a1 = *reinterpret_cast<const float4*>(&u[(size_t)m * 4096 + g * H + j0 + 4]);
    float4 b0 = *reinterpret_cast<const float4*>(&u[(size_t)m * 4096 + 2048 + g * H + j0]);
    float4 b1 = *reinterpret_cast<const float4*>(&u[(size_t)m * 4096 + 2048 + g * H + j0 + 4]);
    float af[8] = {a0.x, a0.y, a0.z, a0.w, a1.x, a1.y, a1.z, a1.w};
    float bf[8] = {b0.x, b0.y, b0.z, b0.w, b1.x, b1.y, b1.z, b1.w};
#pragma unroll
    for (int r = 0; r < 8; r++)
      zfilm[g][r] = (zf[r] - mu) * rs * (1.0f + af[r]) + bf[r];
  }

  float4 c0 = *reinterpret_cast<const float4*>(&c[(size_t)m * H + j0]);
  float4 c1 = *reinterpret_cast<const float4*>(&c[(size_t)m * H + j0 + 4]);
  float cold[8] = {c0.x, c0.y, c0.z, c0.w, c1.x, c1.y, c1.z, c1.w};
  float cnew[8], og[8];
  float s = 0.f, q = 0.f;
#pragma unroll
  for (int r = 0; r < 8; r++) {
    float ig = fsig(zfilm[0][r]);
    float fg = fsig(zfilm[1][r]);
    og[r] = fsig(zfilm[2][r]);
    float gg = ftanh(zfilm[3][r]);
    cnew[r] = fg * cold[r] + ig * gg;
    s += cnew[r]; q += cnew[r] * cnew[r];
  }
#pragma unroll
  for (int off = 32; off >= 1; off >>= 1) {
    s += __shfl_xor(s, off, 64);
    q += __shfl_xor(q, off, 64);
  }
  float mu = s * (1.0f / 512.0f);
  float rs = rsqrtf(q * (1.0f / 512.0f) - mu * mu + 1e-5f);

  float4 g0 = *reinterpret_cast<const float4*>(&gamma[j0]);
  float4 g1 = *reinterpret_cast<const float4*>(&gamma[j0 + 4]);
  float4 e0 = *reinterpret_cast<const float4*>(&beta[j0]);
  float4 e1 = *reinterpret_cast<const float4*>(&beta[j0 + 4]);
  float gam[8] = {g0.x, g0.y, g0.z, g0.w, g1.x, g1.y, g1.z, g1.w};
  float bet[8] = {e0.x, e0.y, e0.z, e0.w, e1.x, e1.y, e1.z, e1.w};
  float hn[8];
#pragma unroll
  for (int r = 0; r < 8; r++) {
    float cn = (cnew[r] - mu) * rs * gam[r] + bet[r];
    hn[r] = og[r] * ftanh(cn);
  }
  float4 h0 = {hn[0], hn[1], hn[2], hn[3]};
  float4 h1 = {hn[4], hn[5], hn[6], hn[7]};
  float4 cn0 = {cnew[0], cnew[1], cnew[2], cnew[3]};
  float4 cn1 = {cnew[4], cnew[5], cnew[6], cnew[7]};
  *reinterpret_cast<float4*>(&out[(size_t)m * H + j0]) = h0;
  *reinterpret_cast<float4*>(&out[(size_t)m * H + j0 + 4]) = h1;
  *reinterpret_cast<float4*>(&out[(size_t)Bn * H + (size_t)m * H + j0]) = cn0;
  *reinterpret_cast<float4*>(&out[(size_t)Bn * H + (size_t)m * H + j0 + 4]) = cn1;
}

extern "C" void kernel_launch(void* const* d_in, const int* in_sizes, int n_in,
                              void* d_out, int out_size, void* d_ws, size_t ws_size,
                              hipStream_t stream) {
  const float* x     = (const float*)d_in[0];
  const float* h     = (const float*)d_in[1];
  const float* c     = (const float*)d_in[2];
  const float* u     = (const float*)d_in[3];
  const float* W     = (const float*)d_in[4];
  const float* blin  = (const float*)d_in[5];
  const float* gamma = (const float*)d_in[6];
  const float* beta  = (const float*)d_in[7];
  float* out = (float*)d_out;

  unsigned short* A  = (unsigned short*)d_ws;          // 32MB
  unsigned short* Bt = A + (size_t)Bn * K;             // 4MB
  unsigned short* Z  = Bt + (size_t)N * K;             // 64MB

  prep_a<<<2048, 256, 0, stream>>>(x, h, A);
  prep_bt<<<dim3(N / 32, K / 32), dim3(32, 8), 0, stream>>>(W, Bt);
  gemm_bt<<<dim3(N / 128, Bn / 128), 256, 0, stream>>>(A, Bt, blin, Z);
  fused_tail<<<Bn / 4, 256, 0, stream>>>(Z, u, c, gamma, beta, out);
}